// Round 7
// baseline (82.642 us; speedup 1.0000x reference)
//
#include <hip/hip_runtime.h>
#include <hip/hip_fp16.h>

namespace {

constexpr int NN   = 256;             // FFT length along each axis
constexpr int BMN  = 256 * 256 * 256; // elements per component
constexpr int LPAD = 272;             // padded float stride per line slice (16B-aligned: 68 float4)

typedef float f4 __attribute__((ext_vector_type(4)));  // native vec: ok for nt builtins

struct cpx { float re, im; };

__device__ __forceinline__ cpx cadd(cpx a, cpx b){ return cpx{a.re + b.re, a.im + b.im}; }
__device__ __forceinline__ cpx csub(cpx a, cpx b){ return cpx{a.re - b.re, a.im - b.im}; }
__device__ __forceinline__ cpx cmul(cpx a, cpx b){ return cpx{a.re*b.re - a.im*b.im, a.re*b.im + a.im*b.re}; }
__device__ __forceinline__ cpx cmuli(cpx a){ return cpx{-a.im, a.re}; }  // multiply by +i (inverse)

// radix-4 inverse butterfly: y[k] = sum_n x[n] * e^{+2pi i nk/4}
__device__ __forceinline__ void r4(cpx a, cpx b, cpx c, cpx d,
                                   cpx& y0, cpx& y1, cpx& y2, cpx& y3) {
  cpx apc = cadd(a, c), amc = csub(a, c);
  cpx bpd = cadd(b, d), bmd = csub(b, d);
  cpx ib  = cmuli(bmd);
  y0 = cadd(apc, bpd);
  y1 = cadd(amc, ib);
  y2 = csub(apc, bpd);
  y3 = csub(amc, ib);
}

// 16-point inverse DFT (unnormalized), natural order in/out, in registers.
__device__ __forceinline__ void ifft16(cpx x[16]) {
  constexpr float WC[10] = { 1.f,  0.9238795325112867f,  0.7071067811865476f,  0.3826834323650898f, 0.f,
                            -0.3826834323650898f, -0.7071067811865476f, -0.9238795325112867f, -1.f,
                            -0.9238795325112867f };
  constexpr float WS[10] = { 0.f,  0.3826834323650898f,  0.7071067811865476f,  0.9238795325112867f, 1.f,
                             0.9238795325112867f,  0.7071067811865476f,  0.3826834323650898f,  0.f,
                            -0.3826834323650898f };
  cpx B[4][4];
#pragma unroll
  for (int n1 = 0; n1 < 4; ++n1)
    r4(x[n1], x[n1 + 4], x[n1 + 8], x[n1 + 12],
       B[n1][0], B[n1][1], B[n1][2], B[n1][3]);
#pragma unroll
  for (int n1 = 1; n1 < 4; ++n1)
#pragma unroll
    for (int k2 = 1; k2 < 4; ++k2)
      B[n1][k2] = cmul(B[n1][k2], cpx{WC[n1 * k2], WS[n1 * k2]});
#pragma unroll
  for (int k2 = 0; k2 < 4; ++k2)
    r4(B[0][k2], B[1][k2], B[2][k2], B[3][k2],
       x[k2], x[k2 + 4], x[k2 + 8], x[k2 + 12]);
}

// multiply a[k1] by W256^{t*k1} = e^{+2pi i t k1/256}
__device__ __forceinline__ void twiddle256(cpx a[16], int t) {
  const float base = 0.024543692606170259f * (float)t;  // 2*pi/256 * t
#pragma unroll
  for (int k1 = 1; k1 < 16; ++k1) {
    float s, c;
    __sincosf(base * (float)k1, &s, &c);
    a[k1] = cmul(a[k1], cpx{c, s});
  }
}

// ------- kernel 1: row IFFT (last axis). fp32 in -> fp16 intermediate in d_ws.
// Input loads are NONTEMPORAL: each element is read exactly once per call, so
// caching the input only evicts the ws intermediate we want L3-resident.
__global__ __launch_bounds__(256)
void k_ifft_rows(const float* __restrict__ xr, const float* __restrict__ xi,
                 __half* __restrict__ wr, __half* __restrict__ wi) {
  __shared__ float Lr[16 * LPAD];
  __shared__ float Li[16 * LPAD];
  const int tid = threadIdx.x;
  const int t   = tid & 15;
  const int ll  = tid >> 4;

  const size_t blk = (size_t)blockIdx.x * (16 * NN);
  const f4* sr4 = reinterpret_cast<const f4*>(xr + blk);
  const f4* si4 = reinterpret_cast<const f4*>(xi + blk);

  // cooperative vector load (1KB contiguous per wave instruction), nt hint
#pragma unroll
  for (int q = 0; q < 4; ++q) {
    const int fi   = (q << 8) + tid;
    const int line = fi >> 6;
    const int slot = fi & 63;
    const f4 vr = __builtin_nontemporal_load(&sr4[fi]);
    const f4 vi = __builtin_nontemporal_load(&si4[fi]);
    *reinterpret_cast<f4*>(&Lr[line * LPAD + slot * 4]) = vr;
    *reinterpret_cast<f4*>(&Li[line * LPAD + slot * 4]) = vi;
  }
  __syncthreads();

  // comb read (ifftshift folded): a[j] = x[(j*16+t)^128] of line ll
  cpx a[16];
  {
    const float* lr = Lr + ll * LPAD;
    const float* li = Li + ll * LPAD;
#pragma unroll
    for (int j = 0; j < 16; ++j) {
      const int idx = (((j << 4) | t) ^ 128);
      a[j] = cpx{ lr[idx], li[idx] };
    }
  }
  ifft16(a);            // a[k1] = A_t[k1]
  twiddle256(a, t);     // * W256^{t*k1}
  __syncthreads();

  // 16x16 transpose (single pass, both components)
  {
    float* lr = Lr + ll * LPAD;
    float* li = Li + ll * LPAD;
#pragma unroll
    for (int k1 = 0; k1 < 16; ++k1) { lr[k1 * 17 + t] = a[k1].re; li[k1 * 17 + t] = a[k1].im; }
    __syncthreads();
#pragma unroll
    for (int n2 = 0; n2 < 16; ++n2) { a[n2].re = lr[t * 17 + n2]; a[n2].im = li[t * 17 + n2]; }
  }
  ifft16(a);            // a[k2] = X[16*k2 + t]
  __syncthreads();

  // stage output in natural line layout (fftshift folded)
  {
    float* lr = Lr + ll * LPAD;
    float* li = Li + ll * LPAD;
#pragma unroll
    for (int k = 0; k < 16; ++k) {
      const int idx = (((k << 4) | t) ^ 128);
      lr[idx] = a[k].re;
      li[idx] = a[k].im;
    }
  }
  __syncthreads();

  // cooperative convert+store fp16 (scale = half of the 1/65536 norm).
  // NOT nontemporal: ws should stay dirty-resident in L3 for cols.
  constexpr float s1 = 1.0f / 256.0f;
  uint2* dr = reinterpret_cast<uint2*>(wr) + (size_t)blockIdx.x * 1024;
  uint2* di = reinterpret_cast<uint2*>(wi) + (size_t)blockIdx.x * 1024;
#pragma unroll
  for (int q = 0; q < 4; ++q) {
    const int fi   = (q << 8) + tid;
    const int line = fi >> 6;
    const int slot = fi & 63;
    const f4 vr = *reinterpret_cast<const f4*>(&Lr[line * LPAD + slot * 4]);
    const f4 vi = *reinterpret_cast<const f4*>(&Li[line * LPAD + slot * 4]);
    union { __half2 h[2]; uint2 u; } pr, pi_;
    pr.h[0]  = __floats2half2_rn(vr.x * s1, vr.y * s1);
    pr.h[1]  = __floats2half2_rn(vr.z * s1, vr.w * s1);
    pi_.h[0] = __floats2half2_rn(vi.x * s1, vi.y * s1);
    pi_.h[1] = __floats2half2_rn(vi.z * s1, vi.w * s1);
    dr[fi] = pr.u;
    di[fi] = pi_.u;
  }
}

// ------- kernel 2: column IFFT (axis -2). fp16 intermediate -> fp32 out.
// 512 threads: c = tid&31 (column, lane-fastest), t = tid>>5. 32-col tiles.
// Reads hit L3 (ws resident); final stores NONTEMPORAL (dead after check).
__global__ __launch_bounds__(512)
void k_ifft_cols(const __half* __restrict__ wr, const __half* __restrict__ wi,
                 float* __restrict__ yr, float* __restrict__ yi) {
  __shared__ float lbuf[32 * 273];
  const int tid = threadIdx.x;
  const int c   = tid & 31;
  const int t   = tid >> 5;
  const int b   = blockIdx.x >> 3;
  const int c0  = (blockIdx.x & 7) << 5;
  const int base = b * 65536 + c0 + c;

  cpx a[16];
#pragma unroll
  for (int j = 0; j < 16; ++j) {
    const int m = (((j << 4) | t) ^ 128);     // ifftshift on load
    a[j] = cpx{ __half2float(wr[base + m * NN]), __half2float(wi[base + m * NN]) };
  }
  ifft16(a);
  twiddle256(a, t);

  // two-pass 16x16 transpose through single buffer (re then im)
  {
    float* L = lbuf + c * 273;
#pragma unroll
    for (int k1 = 0; k1 < 16; ++k1) L[k1 * 17 + t] = a[k1].re;
    __syncthreads();
    float br[16];
#pragma unroll
    for (int n2 = 0; n2 < 16; ++n2) br[n2] = L[t * 17 + n2];
    __syncthreads();
#pragma unroll
    for (int k1 = 0; k1 < 16; ++k1) L[k1 * 17 + t] = a[k1].im;
    __syncthreads();
#pragma unroll
    for (int n2 = 0; n2 < 16; ++n2) { a[n2].im = L[t * 17 + n2]; a[n2].re = br[n2]; }
  }

  ifft16(a);
  constexpr float sc = 1.0f / 256.0f;         // second half of the norm
#pragma unroll
  for (int k = 0; k < 16; ++k) {
    const int m = (((k << 4) | t) ^ 128);     // fftshift on store
    __builtin_nontemporal_store(a[k].re * sc, &yr[base + m * NN]);
    __builtin_nontemporal_store(a[k].im * sc, &yi[base + m * NN]);
  }
}

} // namespace

extern "C" void kernel_launch(void* const* d_in, const int* in_sizes, int n_in,
                              void* d_out, int out_size, void* d_ws, size_t ws_size,
                              hipStream_t stream) {
  const float* xr = (const float*)d_in[0];
  const float* xi = (const float*)d_in[1];
  float* yr = (float*)d_out;        // real part of output
  float* yi = yr + BMN;             // imag part of output
  __half* wr = (__half*)d_ws;       // fp16 intermediate (67 MB, fits ws)
  __half* wi = wr + BMN;

  k_ifft_rows<<<4096, 256, 0, stream>>>(xr, xi, wr, wi);       // 65536 lines / 16
  k_ifft_cols<<<2048, 512, 0, stream>>>(wr, wi, yr, yi);       // 256 images * 8 tiles
}

// Round 8
// 80.779 us; speedup vs baseline: 1.0231x; 1.0231x over previous
//
#include <hip/hip_runtime.h>
#include <hip/hip_fp16.h>

namespace {

constexpr int NN    = 256;             // FFT length along each axis
constexpr int BMN   = 256 * 256 * 256; // elements per component
constexpr int LPAD  = 272;             // padded float stride per line slice
constexpr int TILES = 4;               // tiles (of 16 lines) per rows-block

typedef float f4 __attribute__((ext_vector_type(4)));

struct cpx { float re, im; };

__device__ __forceinline__ cpx cadd(cpx a, cpx b){ return cpx{a.re + b.re, a.im + b.im}; }
__device__ __forceinline__ cpx csub(cpx a, cpx b){ return cpx{a.re - b.re, a.im - b.im}; }
__device__ __forceinline__ cpx cmul(cpx a, cpx b){ return cpx{a.re*b.re - a.im*b.im, a.re*b.im + a.im*b.re}; }
__device__ __forceinline__ cpx cmuli(cpx a){ return cpx{-a.im, a.re}; }  // multiply by +i (inverse)

// radix-4 inverse butterfly: y[k] = sum_n x[n] * e^{+2pi i nk/4}
__device__ __forceinline__ void r4(cpx a, cpx b, cpx c, cpx d,
                                   cpx& y0, cpx& y1, cpx& y2, cpx& y3) {
  cpx apc = cadd(a, c), amc = csub(a, c);
  cpx bpd = cadd(b, d), bmd = csub(b, d);
  cpx ib  = cmuli(bmd);
  y0 = cadd(apc, bpd);
  y1 = cadd(amc, ib);
  y2 = csub(apc, bpd);
  y3 = csub(amc, ib);
}

// 16-point inverse DFT (unnormalized), natural order in/out, in registers.
__device__ __forceinline__ void ifft16(cpx x[16]) {
  constexpr float WC[10] = { 1.f,  0.9238795325112867f,  0.7071067811865476f,  0.3826834323650898f, 0.f,
                            -0.3826834323650898f, -0.7071067811865476f, -0.9238795325112867f, -1.f,
                            -0.9238795325112867f };
  constexpr float WS[10] = { 0.f,  0.3826834323650898f,  0.7071067811865476f,  0.9238795325112867f, 1.f,
                             0.9238795325112867f,  0.7071067811865476f,  0.3826834323650898f,  0.f,
                            -0.3826834323650898f };
  cpx B[4][4];
#pragma unroll
  for (int n1 = 0; n1 < 4; ++n1)
    r4(x[n1], x[n1 + 4], x[n1 + 8], x[n1 + 12],
       B[n1][0], B[n1][1], B[n1][2], B[n1][3]);
#pragma unroll
  for (int n1 = 1; n1 < 4; ++n1)
#pragma unroll
    for (int k2 = 1; k2 < 4; ++k2)
      B[n1][k2] = cmul(B[n1][k2], cpx{WC[n1 * k2], WS[n1 * k2]});
#pragma unroll
  for (int k2 = 0; k2 < 4; ++k2)
    r4(B[0][k2], B[1][k2], B[2][k2], B[3][k2],
       x[k2], x[k2 + 4], x[k2 + 8], x[k2 + 12]);
}

// multiply a[k1] by W256^{t*k1} = e^{+2pi i t k1/256}
__device__ __forceinline__ void twiddle256(cpx a[16], int t) {
  const float base = 0.024543692606170259f * (float)t;  // 2*pi/256 * t
#pragma unroll
  for (int k1 = 1; k1 < 16; ++k1) {
    float s, c;
    __sincosf(base * (float)k1, &s, &c);
    a[k1] = cmul(a[k1], cpx{c, s});
  }
}

// ------- kernel 1: row IFFT (last axis). fp32 in -> fp16 intermediate in ws.
// PIPELINED: each block processes TILES contiguous 16-line tiles; the next
// tile's global loads are issued into registers right after staging the
// current one, so HBM reads stay in flight under the compute/LDS phases
// (rows was duty-cycle-bound: no pipe >40% across 3 structural variants).
__global__ __launch_bounds__(256)
void k_ifft_rows(const float* __restrict__ xr, const float* __restrict__ xi,
                 __half* __restrict__ wr, __half* __restrict__ wi) {
  __shared__ float Lr[16 * LPAD];
  __shared__ float Li[16 * LPAD];
  const int tid = threadIdx.x;
  const int t   = tid & 15;
  const int ll  = tid >> 4;

  const size_t base0 = (size_t)blockIdx.x * (TILES * 16 * NN);

  f4 pr[4], pim[4];
  {
    const f4* sr4 = reinterpret_cast<const f4*>(xr + base0);
    const f4* si4 = reinterpret_cast<const f4*>(xi + base0);
#pragma unroll
    for (int q = 0; q < 4; ++q) {
      const int fi = (q << 8) + tid;
      pr[q]  = sr4[fi];
      pim[q] = si4[fi];
    }
  }

  for (int it = 0; it < TILES; ++it) {
    const size_t tileoff = base0 + (size_t)it * (16 * NN);
    __syncthreads();   // prev iteration's LDS reads (store phase) complete

    // stage prefetched tile into padded LDS
#pragma unroll
    for (int q = 0; q < 4; ++q) {
      const int fi   = (q << 8) + tid;
      const int line = fi >> 6;
      const int slot = fi & 63;
      *reinterpret_cast<f4*>(&Lr[line * LPAD + slot * 4]) = pr[q];
      *reinterpret_cast<f4*>(&Li[line * LPAD + slot * 4]) = pim[q];
    }
    __syncthreads();

    // issue next tile's loads NOW; latency hides under the compute below.
    // (loads precede this tile's stores in vmcnt order, so next iteration's
    // staging waits only on these loads, not the stores)
    if (it + 1 < TILES) {
      const size_t nb = tileoff + (16 * NN);
      const f4* sr4 = reinterpret_cast<const f4*>(xr + nb);
      const f4* si4 = reinterpret_cast<const f4*>(xi + nb);
#pragma unroll
      for (int q = 0; q < 4; ++q) {
        const int fi = (q << 8) + tid;
        pr[q]  = sr4[fi];
        pim[q] = si4[fi];
      }
    }

    // comb read (ifftshift folded): a[j] = x[(j*16+t)^128] of line ll
    cpx a[16];
    {
      const float* lr = Lr + ll * LPAD;
      const float* li = Li + ll * LPAD;
#pragma unroll
      for (int j = 0; j < 16; ++j) {
        const int idx = (((j << 4) | t) ^ 128);
        a[j] = cpx{ lr[idx], li[idx] };
      }
    }
    ifft16(a);            // a[k1] = A_t[k1]
    twiddle256(a, t);     // * W256^{t*k1}
    __syncthreads();

    // 16x16 transpose (single pass, both components)
    {
      float* lr = Lr + ll * LPAD;
      float* li = Li + ll * LPAD;
#pragma unroll
      for (int k1 = 0; k1 < 16; ++k1) { lr[k1 * 17 + t] = a[k1].re; li[k1 * 17 + t] = a[k1].im; }
      __syncthreads();
#pragma unroll
      for (int n2 = 0; n2 < 16; ++n2) { a[n2].re = lr[t * 17 + n2]; a[n2].im = li[t * 17 + n2]; }
    }
    ifft16(a);            // a[k2] = X[16*k2 + t]
    __syncthreads();

    // stage output in natural line layout (fftshift folded)
    {
      float* lr = Lr + ll * LPAD;
      float* li = Li + ll * LPAD;
#pragma unroll
      for (int k = 0; k < 16; ++k) {
        const int idx = (((k << 4) | t) ^ 128);
        lr[idx] = a[k].re;
        li[idx] = a[k].im;
      }
    }
    __syncthreads();

    // cooperative convert+store fp16 (scale = half of the 1/65536 norm).
    // cached (not nt): ws should stay dirty-resident in L3 for cols.
    constexpr float s1 = 1.0f / 256.0f;
    uint2* dr = reinterpret_cast<uint2*>(wr + tileoff);
    uint2* di = reinterpret_cast<uint2*>(wi + tileoff);
#pragma unroll
    for (int q = 0; q < 4; ++q) {
      const int fi   = (q << 8) + tid;
      const int line = fi >> 6;
      const int slot = fi & 63;
      const f4 vr = *reinterpret_cast<const f4*>(&Lr[line * LPAD + slot * 4]);
      const f4 vi = *reinterpret_cast<const f4*>(&Li[line * LPAD + slot * 4]);
      union { __half2 h[2]; uint2 u; } hr, hi;
      hr.h[0] = __floats2half2_rn(vr.x * s1, vr.y * s1);
      hr.h[1] = __floats2half2_rn(vr.z * s1, vr.w * s1);
      hi.h[0] = __floats2half2_rn(vi.x * s1, vi.y * s1);
      hi.h[1] = __floats2half2_rn(vi.z * s1, vi.w * s1);
      dr[fi] = hr.u;
      di[fi] = hi.u;
    }
  }
}

// ------- kernel 2: column IFFT (axis -2). fp16 intermediate -> fp32 out.
// 512 threads: c = tid&31 (column, lane-fastest), t = tid>>5. 32-col tiles.
// Reads hit L3 (ws resident); final stores NONTEMPORAL (dead after check).
__global__ __launch_bounds__(512)
void k_ifft_cols(const __half* __restrict__ wr, const __half* __restrict__ wi,
                 float* __restrict__ yr, float* __restrict__ yi) {
  __shared__ float lbuf[32 * 273];
  const int tid = threadIdx.x;
  const int c   = tid & 31;
  const int t   = tid >> 5;
  const int b   = blockIdx.x >> 3;
  const int c0  = (blockIdx.x & 7) << 5;
  const int base = b * 65536 + c0 + c;

  cpx a[16];
#pragma unroll
  for (int j = 0; j < 16; ++j) {
    const int m = (((j << 4) | t) ^ 128);     // ifftshift on load
    a[j] = cpx{ __half2float(wr[base + m * NN]), __half2float(wi[base + m * NN]) };
  }
  ifft16(a);
  twiddle256(a, t);

  // two-pass 16x16 transpose through single buffer (re then im)
  {
    float* L = lbuf + c * 273;
#pragma unroll
    for (int k1 = 0; k1 < 16; ++k1) L[k1 * 17 + t] = a[k1].re;
    __syncthreads();
    float br[16];
#pragma unroll
    for (int n2 = 0; n2 < 16; ++n2) br[n2] = L[t * 17 + n2];
    __syncthreads();
#pragma unroll
    for (int k1 = 0; k1 < 16; ++k1) L[k1 * 17 + t] = a[k1].im;
    __syncthreads();
#pragma unroll
    for (int n2 = 0; n2 < 16; ++n2) { a[n2].im = L[t * 17 + n2]; a[n2].re = br[n2]; }
  }

  ifft16(a);
  constexpr float sc = 1.0f / 256.0f;         // second half of the norm
#pragma unroll
  for (int k = 0; k < 16; ++k) {
    const int m = (((k << 4) | t) ^ 128);     // fftshift on store
    __builtin_nontemporal_store(a[k].re * sc, &yr[base + m * NN]);
    __builtin_nontemporal_store(a[k].im * sc, &yi[base + m * NN]);
  }
}

} // namespace

extern "C" void kernel_launch(void* const* d_in, const int* in_sizes, int n_in,
                              void* d_out, int out_size, void* d_ws, size_t ws_size,
                              hipStream_t stream) {
  const float* xr = (const float*)d_in[0];
  const float* xi = (const float*)d_in[1];
  float* yr = (float*)d_out;        // real part of output
  float* yi = yr + BMN;             // imag part of output
  __half* wr = (__half*)d_ws;       // fp16 intermediate (67 MB, fits ws)
  __half* wi = wr + BMN;

  k_ifft_rows<<<1024, 256, 0, stream>>>(xr, xi, wr, wi);   // 1024 blocks x 4 tiles
  k_ifft_cols<<<2048, 512, 0, stream>>>(wr, wi, yr, yi);   // 256 images * 8 tiles
}